// Round 16
// baseline (858.517 us; speedup 1.0000x reference)
//
#include <hip/hip_runtime.h>
#include <math.h>

#define B_DIM 512
#define K_DIM 2048
#define N_DIM 4096
#define BRN 16
#define NUM_TARGET 4096

#define THR_MIN 0.5
#define THR_MAX 2.0
#define REFRACT 2.0f
#define LN_EPS 1e-5

typedef __attribute__((ext_vector_type(4))) double d4_t;

// ===== GEMM (f64 MFMA, verified layout, single-barrier double-buffer) =======
// Verified maps (R14): A[row=l&15][k=l>>4]; B[k=l>>4][col=l&15];
//                      D reg q -> row=(l>>4)+4*q, col=l&15.
#define BM 64
#define BN 64
#define BKK 32
#define LDK 34

__global__ __launch_bounds__(256) void gemm_mfma64_db_kernel(
    const float* __restrict__ X,    // [B, K]
    const float* __restrict__ W,    // [N, K]
    const float* __restrict__ bias, // [N]
    float* __restrict__ dhi,        // [B, N]  (new_mem slice)
    float* __restrict__ dlo)        // [B, N]  (spike slice)
{
    __shared__ double As[2][BM][LDK];  // 2 x 17 KB
    __shared__ double Bs[2][BN][LDK];  // 2 x 17 KB  -> 68 KB total

    const int t    = threadIdx.x;
    const int lane = t & 63;
    const int wv   = t >> 6;
    const int wr   = (wv >> 1) * 32;
    const int wc   = (wv & 1) * 32;
    const int l15  = lane & 15;
    const int lg   = lane >> 4;

    const int row0 = blockIdx.x * BM;
    const int col0 = blockIdx.y * BN;

    const int sr = t >> 3;          // 0..31
    const int sk = (t & 7) * 4;     // 0,4,...,28
    const float* xp0 = &X[(size_t)(row0 + sr) * K_DIM + sk];
    const float* xp1 = xp0 + (size_t)32 * K_DIM;
    const float* wp0 = &W[(size_t)(col0 + sr) * K_DIM + sk];
    const float* wp1 = wp0 + (size_t)32 * K_DIM;

    d4_t acc00 = {0.,0.,0.,0.}, acc01 = {0.,0.,0.,0.};
    d4_t acc10 = {0.,0.,0.,0.}, acc11 = {0.,0.,0.,0.};

    float4 xa0 = *(const float4*)(xp0);
    float4 xa1 = *(const float4*)(xp1);
    float4 wb0 = *(const float4*)(wp0);
    float4 wb1 = *(const float4*)(wp1);

#define STAGE(P)                                                              \
    As[P][sr     ][sk+0] = (double)xa0.x; As[P][sr     ][sk+1] = (double)xa0.y; \
    As[P][sr     ][sk+2] = (double)xa0.z; As[P][sr     ][sk+3] = (double)xa0.w; \
    As[P][sr + 32][sk+0] = (double)xa1.x; As[P][sr + 32][sk+1] = (double)xa1.y; \
    As[P][sr + 32][sk+2] = (double)xa1.z; As[P][sr + 32][sk+3] = (double)xa1.w; \
    Bs[P][sr     ][sk+0] = (double)wb0.x; Bs[P][sr     ][sk+1] = (double)wb0.y; \
    Bs[P][sr     ][sk+2] = (double)wb0.z; Bs[P][sr     ][sk+3] = (double)wb0.w; \
    Bs[P][sr + 32][sk+0] = (double)wb1.x; Bs[P][sr + 32][sk+1] = (double)wb1.y; \
    Bs[P][sr + 32][sk+2] = (double)wb1.z; Bs[P][sr + 32][sk+3] = (double)wb1.w;

    STAGE(0);
    __syncthreads();

    int cur = 0;
    for (int k0 = 0; k0 < K_DIM; k0 += BKK) {
        const bool haveNext = (k0 + BKK < K_DIM);
        if (haveNext) {            // issue next-tile loads; land after MFMA
            xa0 = *(const float4*)(xp0 + k0 + BKK);
            xa1 = *(const float4*)(xp1 + k0 + BKK);
            wb0 = *(const float4*)(wp0 + k0 + BKK);
            wb1 = *(const float4*)(wp1 + k0 + BKK);
        }

        #pragma unroll
        for (int kk = 0; kk < BKK; kk += 4) {
            double a0 = As[cur][wr      + l15][kk + lg];
            double a1 = As[cur][wr + 16 + l15][kk + lg];
            double b0 = Bs[cur][wc      + l15][kk + lg];
            double b1 = Bs[cur][wc + 16 + l15][kk + lg];
#ifdef __HIP_DEVICE_COMPILE__
            acc00 = __builtin_amdgcn_mfma_f64_16x16x4f64(a0, b0, acc00, 0, 0, 0);
            acc01 = __builtin_amdgcn_mfma_f64_16x16x4f64(a0, b1, acc01, 0, 0, 0);
            acc10 = __builtin_amdgcn_mfma_f64_16x16x4f64(a1, b0, acc10, 0, 0, 0);
            acc11 = __builtin_amdgcn_mfma_f64_16x16x4f64(a1, b1, acc11, 0, 0, 0);
#else
            acc00[0] += a0 * b0; acc01[0] += a0 * b1;
            acc10[0] += a1 * b0; acc11[0] += a1 * b1;
#endif
        }

        if (haveNext) { STAGE(cur ^ 1); }
        __syncthreads();
        cur ^= 1;
    }
#undef STAGE

    #pragma unroll
    for (int i = 0; i < 2; ++i) {
        #pragma unroll
        for (int j = 0; j < 2; ++j) {
            d4_t a = (i == 0) ? (j == 0 ? acc00 : acc01)
                              : (j == 0 ? acc10 : acc11);
            const int cl = col0 + wc + j * 16 + l15;
            const double bd = (double)bias[cl];
            #pragma unroll
            for (int q = 0; q < 4; ++q) {
                const int rl = row0 + wr + i * 16 + lg + 4 * q;
                double v = a[q] + bd;
                float hv = (float)v;
                float lv = (float)(v - (double)hv);
                dhi[(size_t)rl * N_DIM + cl] = hv;
                dlo[(size_t)rl * N_DIM + cl] = lv;
            }
        }
    }
}

// ===== shared helpers ======================================================
__device__ inline float pow09(int d) {
    switch (d) {
        case 0: return 1.0f;
        case 1: return 0.9f;
        case 2: return 0.81f;
        case 3: return 0.729f;
        case 4: return 0.6561f;
        case 5: return 0.59049f;
        default: return powf(0.9f, (float)d);
    }
}

// ===== fused-clone DIAGNOSIS PROBE (3 reps, checksum out, floods top-5) =====
__global__ __launch_bounds__(1024) void fused_probe_kernel(
    const float* __restrict__ dhi, const float* __restrict__ dlo,
    const float* __restrict__ mem_i, const float* __restrict__ ref_i,
    const float* __restrict__ gamma, const float* __restrict__ beta,
    const float* __restrict__ thr_p, const float* __restrict__ dec_p,
    const float* __restrict__ att, const int* __restrict__ tgt,
    const int* __restrict__ dly,
    float* __restrict__ chk)
{
    __shared__ float  sm_axon[NUM_TARGET];
    __shared__ double red[16];
    __shared__ double red2[16];

    const int t = threadIdx.x;
    const int lane = t & 63;
    const int wv = t >> 6;
    const int b0 = blockIdx.x;
    float checksum = 0.f;

    ((float4*)sm_axon)[t] = make_float4(0.f, 0.f, 0.f, 0.f);

    for (int rep = 0; rep < 3; ++rep) {
        const int b   = (b0 + rep * 131) & (B_DIM - 1);
        const int idx = (t + rep * 16) & 1023;        // rotated, still coalesced

        const float4 h = ((const float4*)(dhi + (size_t)b * N_DIM))[idx];
        const float4 l = ((const float4*)(dlo + (size_t)b * N_DIM))[idx];
        double d0 = (double)h.x + (double)l.x;
        double d1 = (double)h.y + (double)l.y;
        double d2 = (double)h.z + (double)l.z;
        double d3 = (double)h.w + (double)l.w;

        double s = d0 + d1 + d2 + d3;
        #pragma unroll
        for (int o = 32; o > 0; o >>= 1) s += __shfl_down(s, o, 64);
        if (lane == 0) red[wv] = s;
        __syncthreads();
        double mu = 0.0;
        #pragma unroll
        for (int i = 0; i < 16; ++i) mu += red[i];
        mu *= (1.0 / 4096.0);

        double e0 = d0 - mu, e1 = d1 - mu, e2 = d2 - mu, e3 = d3 - mu;
        double vs = e0*e0 + e1*e1 + e2*e2 + e3*e3;
        #pragma unroll
        for (int o = 32; o > 0; o >>= 1) vs += __shfl_down(vs, o, 64);
        if (lane == 0) red2[wv] = vs;
        __syncthreads();
        double var = 0.0;
        #pragma unroll
        for (int i = 0; i < 16; ++i) var += red2[i];
        var *= (1.0 / 4096.0);
        const double rstd = 1.0 / sqrt(var + LN_EPS);

        const float4 g4 = ((const float4*)gamma)[idx];
        const float4 be4 = ((const float4*)beta)[idx];
        const float4 th4 = ((const float4*)thr_p)[idx];
        const float4 dc4 = ((const float4*)dec_p)[idx];
        const float4 mi4 = ((const float4*)(mem_i + (size_t)b * N_DIM))[idx];
        const float4 ri4 = ((const float4*)(ref_i + (size_t)b * N_DIM))[idx];

        const double dd[4] = {d0, d1, d2, d3};
        const float gg[4] = {g4.x, g4.y, g4.z, g4.w};
        const float bb[4] = {be4.x, be4.y, be4.z, be4.w};
        const float tt[4] = {th4.x, th4.y, th4.z, th4.w};
        const float cc[4] = {dc4.x, dc4.y, dc4.z, dc4.w};
        const float mm[4] = {mi4.x, mi4.y, mi4.z, mi4.w};
        const float rr[4] = {ri4.x, ri4.y, ri4.z, ri4.w};

        #pragma unroll
        for (int q = 0; q < 4; ++q) {
            double dv = (dd[q] - mu) * rstd * (double)gg[q] + (double)bb[q];
            double dcl = fmin(fmax((double)cc[q], 0.0), 1.0);
            double th = fmin(fmax((double)tt[q], THR_MIN), THR_MAX);
            float  rf = rr[q];
            double nm = dcl * (double)mm[q] + dv;
            bool   fired = (nm >= th) && (rf <= 0.f);
            if (fired) nm -= th;
            float nmf = (float)nm;
            float sp = fired ? 1.f : 0.f;
            float nr = fired ? REFRACT : fmaxf(rf - 1.f, 0.f);
            float sig = sp + 0.1f * (1.0f / (1.0f + expf(-nmf)));
            checksum += sp + nmf + nr;

            const int base = (idx * 4 + q) * BRN;
            #pragma unroll
            for (int j = 0; j < BRN; j += 4) {
                int4 t4 = *(const int4*)&tgt[base + j];
                float4 a4 = *(const float4*)&att[base + j];
                int4  dd4 = *(const int4*)&dly[base + j];
                float f0 = fminf(fmaxf(a4.x,0.f),1.f) * pow09(dd4.x);
                float f1 = fminf(fmaxf(a4.y,0.f),1.f) * pow09(dd4.y);
                float f2 = fminf(fmaxf(a4.z,0.f),1.f) * pow09(dd4.z);
                float f3 = fminf(fmaxf(a4.w,0.f),1.f) * pow09(dd4.w);
                atomicAdd(&sm_axon[t4.x], sig * f0);
                atomicAdd(&sm_axon[t4.y], sig * f1);
                atomicAdd(&sm_axon[t4.z], sig * f2);
                atomicAdd(&sm_axon[t4.w], sig * f3);
            }
        }
        __syncthreads();   // red[]/red2[] reuse + sm_axon settle for next rep
    }

    float4 ax = ((const float4*)sm_axon)[t];
    checksum += ax.x + ax.y + ax.z + ax.w;
    chk[(size_t)b0 * 1024 + t] = checksum;
}

// ===== fused LN + soma + scatter (R11/R15 production, unchanged) ============
__global__ __launch_bounds__(1024) void fused_row_kernel(
    const float* __restrict__ dhi, const float* __restrict__ dlo,
    const float* __restrict__ mem_i, const float* __restrict__ ref_i,
    const float* __restrict__ gamma, const float* __restrict__ beta,
    const float* __restrict__ thr_p, const float* __restrict__ dec_p,
    const float* __restrict__ att, const int* __restrict__ tgt,
    const int* __restrict__ dly,
    float* __restrict__ axon_o, float* __restrict__ spike_o,
    float* __restrict__ mem_o, float* __restrict__ ref_o)
{
    __shared__ float  sm_axon[NUM_TARGET];
    __shared__ double red[16];
    __shared__ double red2[16];

    const int b = blockIdx.x;
    const int t = threadIdx.x;
    const int lane = t & 63;
    const int wv = t >> 6;

    ((float4*)sm_axon)[t] = make_float4(0.f, 0.f, 0.f, 0.f);

    const float4 h = ((const float4*)(dhi + (size_t)b * N_DIM))[t];
    const float4 l = ((const float4*)(dlo + (size_t)b * N_DIM))[t];
    double d0 = (double)h.x + (double)l.x;
    double d1 = (double)h.y + (double)l.y;
    double d2 = (double)h.z + (double)l.z;
    double d3 = (double)h.w + (double)l.w;

    double s = d0 + d1 + d2 + d3;
    #pragma unroll
    for (int o = 32; o > 0; o >>= 1) s += __shfl_down(s, o, 64);
    if (lane == 0) red[wv] = s;
    __syncthreads();
    double mu = 0.0;
    #pragma unroll
    for (int i = 0; i < 16; ++i) mu += red[i];
    mu *= (1.0 / 4096.0);

    double e0 = d0 - mu, e1 = d1 - mu, e2 = d2 - mu, e3 = d3 - mu;
    double vs = e0*e0 + e1*e1 + e2*e2 + e3*e3;
    #pragma unroll
    for (int o = 32; o > 0; o >>= 1) vs += __shfl_down(vs, o, 64);
    if (lane == 0) red2[wv] = vs;
    __syncthreads();
    double var = 0.0;
    #pragma unroll
    for (int i = 0; i < 16; ++i) var += red2[i];
    var *= (1.0 / 4096.0);
    const double rstd = 1.0 / sqrt(var + LN_EPS);

    const float4 g4 = ((const float4*)gamma)[t];
    const float4 be4 = ((const float4*)beta)[t];
    const float4 th4 = ((const float4*)thr_p)[t];
    const float4 dc4 = ((const float4*)dec_p)[t];
    const float4 mi4 = ((const float4*)(mem_i + (size_t)b * N_DIM))[t];
    const float4 ri4 = ((const float4*)(ref_i + (size_t)b * N_DIM))[t];

    float4 sp4, nm4, nr4, sg4;
    {
        const double dd[4] = {d0, d1, d2, d3};
        const float gg[4] = {g4.x, g4.y, g4.z, g4.w};
        const float bb[4] = {be4.x, be4.y, be4.z, be4.w};
        const float tt[4] = {th4.x, th4.y, th4.z, th4.w};
        const float cc[4] = {dc4.x, dc4.y, dc4.z, dc4.w};
        const float mm[4] = {mi4.x, mi4.y, mi4.z, mi4.w};
        const float rr[4] = {ri4.x, ri4.y, ri4.z, ri4.w};
        float spv[4], nmv[4], nrv[4], sgv[4];
        #pragma unroll
        for (int q = 0; q < 4; ++q) {
            double dv = (dd[q] - mu) * rstd * (double)gg[q] + (double)bb[q];
            double dcl = fmin(fmax((double)cc[q], 0.0), 1.0);
            double th = fmin(fmax((double)tt[q], THR_MIN), THR_MAX);
            float  rf = rr[q];
            double nm = dcl * (double)mm[q] + dv;
            bool   fired = (nm >= th) && (rf <= 0.f);
            if (fired) nm -= th;
            float nmf = (float)nm;
            spv[q] = fired ? 1.f : 0.f;
            nmv[q] = nmf;
            nrv[q] = fired ? REFRACT : fmaxf(rf - 1.f, 0.f);
            sgv[q] = spv[q] + 0.1f * (1.0f / (1.0f + expf(-nmf)));
        }
        sp4 = make_float4(spv[0], spv[1], spv[2], spv[3]);
        nm4 = make_float4(nmv[0], nmv[1], nmv[2], nmv[3]);
        nr4 = make_float4(nrv[0], nrv[1], nrv[2], nrv[3]);
        sg4 = make_float4(sgv[0], sgv[1], sgv[2], sgv[3]);
    }
    ((float4*)(spike_o + (size_t)b * N_DIM))[t] = sp4;
    ((float4*)(mem_o   + (size_t)b * N_DIM))[t] = nm4;
    ((float4*)(ref_o   + (size_t)b * N_DIM))[t] = nr4;

    const float sgv[4] = {sg4.x, sg4.y, sg4.z, sg4.w};
    #pragma unroll
    for (int q = 0; q < 4; ++q) {
        const float sig = sgv[q];
        const int base = (t * 4 + q) * BRN;
        #pragma unroll
        for (int j = 0; j < BRN; j += 4) {
            int4 t4 = *(const int4*)&tgt[base + j];
            float4 a4 = *(const float4*)&att[base + j];
            int4  dd4 = *(const int4*)&dly[base + j];
            float f0 = fminf(fmaxf(a4.x,0.f),1.f) * pow09(dd4.x);
            float f1 = fminf(fmaxf(a4.y,0.f),1.f) * pow09(dd4.y);
            float f2 = fminf(fmaxf(a4.z,0.f),1.f) * pow09(dd4.z);
            float f3 = fminf(fmaxf(a4.w,0.f),1.f) * pow09(dd4.w);
            atomicAdd(&sm_axon[t4.x], sig * f0);
            atomicAdd(&sm_axon[t4.y], sig * f1);
            atomicAdd(&sm_axon[t4.z], sig * f2);
            atomicAdd(&sm_axon[t4.w], sig * f3);
        }
    }
    __syncthreads();

    ((float4*)(axon_o + (size_t)b * NUM_TARGET))[t] = ((const float4*)sm_axon)[t];
}

extern "C" void kernel_launch(void* const* d_in, const int* in_sizes, int n_in,
                              void* d_out, int out_size, void* d_ws, size_t ws_size,
                              hipStream_t stream) {
    const float* x     = (const float*)d_in[0];
    const float* mem   = (const float*)d_in[1];
    const float* refr  = (const float*)d_in[2];
    const float* W     = (const float*)d_in[3];
    const float* bias  = (const float*)d_in[4];
    const float* gamma = (const float*)d_in[5];
    const float* beta  = (const float*)d_in[6];
    const float* thr   = (const float*)d_in[7];
    const float* dec   = (const float*)d_in[8];
    const float* att   = (const float*)d_in[9];
    const int*   tgt   = (const int*)d_in[10];
    const int*   dly   = (const int*)d_in[11];

    float* out   = (float*)d_out;
    const int SEC = B_DIM * N_DIM;
    float* axon  = out;
    float* spike = out + SEC;
    float* nmem  = out + 2 * SEC;
    float* nref  = out + 3 * SEC;
    float* dhi   = nmem;
    float* dlo   = spike;

    dim3 gg(B_DIM / BM, N_DIM / BN);   // 8 x 64
    gemm_mfma64_db_kernel<<<gg, 256, 0, stream>>>(x, W, bias, dhi, dlo);

    // diagnosis probe: fused clone x3 reps, checksum into axon slice
    // (axon fully overwritten by production fused below)
    fused_probe_kernel<<<B_DIM, 1024, 0, stream>>>(
        dhi, dlo, mem, refr, gamma, beta, thr, dec, att, tgt, dly, axon);

    fused_row_kernel<<<B_DIM, 1024, 0, stream>>>(
        dhi, dlo, mem, refr, gamma, beta, thr, dec, att, tgt, dly,
        axon, spike, nmem, nref);
}

// Round 17
// 346.623 us; speedup vs baseline: 2.4768x; 2.4768x over previous
//
#include <hip/hip_runtime.h>
#include <math.h>

#define B_DIM 512
#define K_DIM 2048
#define N_DIM 4096
#define BRN 16
#define NUM_TARGET 4096

#define THR_MIN 0.5
#define THR_MAX 2.0
#define REFRACT 2.0f
#define LN_EPS 1e-5

typedef __attribute__((ext_vector_type(4))) double d4_t;

// ===== GEMM (f64 MFMA, verified layout, single-barrier double-buffer) =======
// Verified maps (R14): A[row=l&15][k=l>>4]; B[k=l>>4][col=l&15];
//                      D reg q -> row=(l>>4)+4*q, col=l&15.
#define BM 64
#define BN 64
#define BKK 32
#define LDK 34

__global__ __launch_bounds__(256) void gemm_mfma64_db_kernel(
    const float* __restrict__ X, const float* __restrict__ W,
    const float* __restrict__ bias,
    float* __restrict__ dhi, float* __restrict__ dlo)
{
    __shared__ double As[2][BM][LDK];
    __shared__ double Bs[2][BN][LDK];

    const int t    = threadIdx.x;
    const int lane = t & 63;
    const int wv   = t >> 6;
    const int wr   = (wv >> 1) * 32;
    const int wc   = (wv & 1) * 32;
    const int l15  = lane & 15;
    const int lg   = lane >> 4;

    const int row0 = blockIdx.x * BM;
    const int col0 = blockIdx.y * BN;

    const int sr = t >> 3;
    const int sk = (t & 7) * 4;
    const float* xp0 = &X[(size_t)(row0 + sr) * K_DIM + sk];
    const float* xp1 = xp0 + (size_t)32 * K_DIM;
    const float* wp0 = &W[(size_t)(col0 + sr) * K_DIM + sk];
    const float* wp1 = wp0 + (size_t)32 * K_DIM;

    d4_t acc00 = {0.,0.,0.,0.}, acc01 = {0.,0.,0.,0.};
    d4_t acc10 = {0.,0.,0.,0.}, acc11 = {0.,0.,0.,0.};

    float4 xa0 = *(const float4*)(xp0);
    float4 xa1 = *(const float4*)(xp1);
    float4 wb0 = *(const float4*)(wp0);
    float4 wb1 = *(const float4*)(wp1);

#define STAGE(P)                                                              \
    As[P][sr     ][sk+0] = (double)xa0.x; As[P][sr     ][sk+1] = (double)xa0.y; \
    As[P][sr     ][sk+2] = (double)xa0.z; As[P][sr     ][sk+3] = (double)xa0.w; \
    As[P][sr + 32][sk+0] = (double)xa1.x; As[P][sr + 32][sk+1] = (double)xa1.y; \
    As[P][sr + 32][sk+2] = (double)xa1.z; As[P][sr + 32][sk+3] = (double)xa1.w; \
    Bs[P][sr     ][sk+0] = (double)wb0.x; Bs[P][sr     ][sk+1] = (double)wb0.y; \
    Bs[P][sr     ][sk+2] = (double)wb0.z; Bs[P][sr     ][sk+3] = (double)wb0.w; \
    Bs[P][sr + 32][sk+0] = (double)wb1.x; Bs[P][sr + 32][sk+1] = (double)wb1.y; \
    Bs[P][sr + 32][sk+2] = (double)wb1.z; Bs[P][sr + 32][sk+3] = (double)wb1.w;

    STAGE(0);
    __syncthreads();

    int cur = 0;
    for (int k0 = 0; k0 < K_DIM; k0 += BKK) {
        const bool haveNext = (k0 + BKK < K_DIM);
        if (haveNext) {
            xa0 = *(const float4*)(xp0 + k0 + BKK);
            xa1 = *(const float4*)(xp1 + k0 + BKK);
            wb0 = *(const float4*)(wp0 + k0 + BKK);
            wb1 = *(const float4*)(wp1 + k0 + BKK);
        }

        #pragma unroll
        for (int kk = 0; kk < BKK; kk += 4) {
            double a0 = As[cur][wr      + l15][kk + lg];
            double a1 = As[cur][wr + 16 + l15][kk + lg];
            double b0 = Bs[cur][wc      + l15][kk + lg];
            double b1 = Bs[cur][wc + 16 + l15][kk + lg];
#ifdef __HIP_DEVICE_COMPILE__
            acc00 = __builtin_amdgcn_mfma_f64_16x16x4f64(a0, b0, acc00, 0, 0, 0);
            acc01 = __builtin_amdgcn_mfma_f64_16x16x4f64(a0, b1, acc01, 0, 0, 0);
            acc10 = __builtin_amdgcn_mfma_f64_16x16x4f64(a1, b0, acc10, 0, 0, 0);
            acc11 = __builtin_amdgcn_mfma_f64_16x16x4f64(a1, b1, acc11, 0, 0, 0);
#else
            acc00[0] += a0 * b0; acc01[0] += a0 * b1;
            acc10[0] += a1 * b0; acc11[0] += a1 * b1;
#endif
        }

        if (haveNext) { STAGE(cur ^ 1); }
        __syncthreads();
        cur ^= 1;
    }
#undef STAGE

    #pragma unroll
    for (int i = 0; i < 2; ++i) {
        #pragma unroll
        for (int j = 0; j < 2; ++j) {
            d4_t a = (i == 0) ? (j == 0 ? acc00 : acc01)
                              : (j == 0 ? acc10 : acc11);
            const int cl = col0 + wc + j * 16 + l15;
            const double bd = (double)bias[cl];
            #pragma unroll
            for (int q = 0; q < 4; ++q) {
                const int rl = row0 + wr + i * 16 + lg + 4 * q;
                double v = a[q] + bd;
                float hv = (float)v;
                float lv = (float)(v - (double)hv);
                dhi[(size_t)rl * N_DIM + cl] = hv;
                dlo[(size_t)rl * N_DIM + cl] = lv;
            }
        }
    }
}

// ===== helpers ==============================================================
__device__ inline float pow09(int d) {
    switch (d) {
        case 0: return 1.0f;
        case 1: return 0.9f;
        case 2: return 0.81f;
        case 3: return 0.729f;
        case 4: return 0.6561f;
        case 5: return 0.59049f;
        default: return powf(0.9f, (float)d);
    }
}

// ===== pack kernel: (tgt u16 | fac bf16) per branch, 4 B ====================
__global__ __launch_bounds__(256) void pack_kernel(
    const float* __restrict__ att, const int* __restrict__ tgt,
    const int* __restrict__ dly, unsigned int* __restrict__ packed)
{
    int i = blockIdx.x * 256 + threadIdx.x;     // 65536 total
    float a = fminf(fmaxf(att[i], 0.f), 1.f);
    float f = a * pow09(dly[i]);
    unsigned int u = __float_as_uint(f);
    u += 0x7FFFu + ((u >> 16) & 1u);            // round-to-nearest-even bf16
    packed[i] = (unsigned int)(tgt[i] & 0xFFFF) | (u & 0xFFFF0000u);
}

// ===== fused LN + soma + scatter ===========================================
template <int PACKED>
__global__ __launch_bounds__(1024) void fused_row_kernel(
    const float* __restrict__ dhi, const float* __restrict__ dlo,
    const float* __restrict__ mem_i, const float* __restrict__ ref_i,
    const float* __restrict__ gamma, const float* __restrict__ beta,
    const float* __restrict__ thr_p, const float* __restrict__ dec_p,
    const float* __restrict__ att, const int* __restrict__ tgt,
    const int* __restrict__ dly, const unsigned int* __restrict__ pk,
    float* __restrict__ axon_o, float* __restrict__ spike_o,
    float* __restrict__ mem_o, float* __restrict__ ref_o)
{
    __shared__ float  sm_axon[NUM_TARGET];
    __shared__ double red[16];
    __shared__ double red2[16];

    const int b = blockIdx.x;
    const int t = threadIdx.x;
    const int lane = t & 63;
    const int wv = t >> 6;

    ((float4*)sm_axon)[t] = make_float4(0.f, 0.f, 0.f, 0.f);

    const float4 h = ((const float4*)(dhi + (size_t)b * N_DIM))[t];
    const float4 l = ((const float4*)(dlo + (size_t)b * N_DIM))[t];
    double d0 = (double)h.x + (double)l.x;
    double d1 = (double)h.y + (double)l.y;
    double d2 = (double)h.z + (double)l.z;
    double d3 = (double)h.w + (double)l.w;

    double s = d0 + d1 + d2 + d3;
    #pragma unroll
    for (int o = 32; o > 0; o >>= 1) s += __shfl_down(s, o, 64);
    if (lane == 0) red[wv] = s;
    __syncthreads();
    double mu = 0.0;
    #pragma unroll
    for (int i = 0; i < 16; ++i) mu += red[i];
    mu *= (1.0 / 4096.0);

    double e0 = d0 - mu, e1 = d1 - mu, e2 = d2 - mu, e3 = d3 - mu;
    double vs = e0*e0 + e1*e1 + e2*e2 + e3*e3;
    #pragma unroll
    for (int o = 32; o > 0; o >>= 1) vs += __shfl_down(vs, o, 64);
    if (lane == 0) red2[wv] = vs;
    __syncthreads();
    double var = 0.0;
    #pragma unroll
    for (int i = 0; i < 16; ++i) var += red2[i];
    var *= (1.0 / 4096.0);
    const double rstd = 1.0 / sqrt(var + LN_EPS);

    const float4 g4 = ((const float4*)gamma)[t];
    const float4 be4 = ((const float4*)beta)[t];
    const float4 th4 = ((const float4*)thr_p)[t];
    const float4 dc4 = ((const float4*)dec_p)[t];
    const float4 mi4 = ((const float4*)(mem_i + (size_t)b * N_DIM))[t];
    const float4 ri4 = ((const float4*)(ref_i + (size_t)b * N_DIM))[t];

    float4 sp4, nm4, nr4, sg4;
    {
        const double dd[4] = {d0, d1, d2, d3};
        const float gg[4] = {g4.x, g4.y, g4.z, g4.w};
        const float bb[4] = {be4.x, be4.y, be4.z, be4.w};
        const float tt[4] = {th4.x, th4.y, th4.z, th4.w};
        const float cc[4] = {dc4.x, dc4.y, dc4.z, dc4.w};
        const float mm[4] = {mi4.x, mi4.y, mi4.z, mi4.w};
        const float rr[4] = {ri4.x, ri4.y, ri4.z, ri4.w};
        float spv[4], nmv[4], nrv[4], sgv[4];
        #pragma unroll
        for (int q = 0; q < 4; ++q) {
            double dv = (dd[q] - mu) * rstd * (double)gg[q] + (double)bb[q];
            double dcl = fmin(fmax((double)cc[q], 0.0), 1.0);
            double th = fmin(fmax((double)tt[q], THR_MIN), THR_MAX);
            float  rf = rr[q];
            double nm = dcl * (double)mm[q] + dv;
            bool   fired = (nm >= th) && (rf <= 0.f);
            if (fired) nm -= th;
            float nmf = (float)nm;
            spv[q] = fired ? 1.f : 0.f;
            nmv[q] = nmf;
            nrv[q] = fired ? REFRACT : fmaxf(rf - 1.f, 0.f);
            sgv[q] = spv[q] + 0.1f * (1.0f / (1.0f + expf(-nmf)));
        }
        sp4 = make_float4(spv[0], spv[1], spv[2], spv[3]);
        nm4 = make_float4(nmv[0], nmv[1], nmv[2], nmv[3]);
        nr4 = make_float4(nrv[0], nrv[1], nrv[2], nrv[3]);
        sg4 = make_float4(sgv[0], sgv[1], sgv[2], sgv[3]);
    }
    ((float4*)(spike_o + (size_t)b * N_DIM))[t] = sp4;
    ((float4*)(mem_o   + (size_t)b * N_DIM))[t] = nm4;
    ((float4*)(ref_o   + (size_t)b * N_DIM))[t] = nr4;

    const float sgv[4] = {sg4.x, sg4.y, sg4.z, sg4.w};
    #pragma unroll
    for (int q = 0; q < 4; ++q) {
        const float sig = sgv[q];
        const int base = (t * 4 + q) * BRN;
        if (PACKED) {
            #pragma unroll
            for (int j = 0; j < BRN; j += 4) {
                uint4 p4 = *(const uint4*)&pk[base + j];
                atomicAdd(&sm_axon[p4.x & 0xFFFFu], sig * __uint_as_float(p4.x & 0xFFFF0000u));
                atomicAdd(&sm_axon[p4.y & 0xFFFFu], sig * __uint_as_float(p4.y & 0xFFFF0000u));
                atomicAdd(&sm_axon[p4.z & 0xFFFFu], sig * __uint_as_float(p4.z & 0xFFFF0000u));
                atomicAdd(&sm_axon[p4.w & 0xFFFFu], sig * __uint_as_float(p4.w & 0xFFFF0000u));
            }
        } else {
            #pragma unroll
            for (int j = 0; j < BRN; j += 4) {
                int4 t4 = *(const int4*)&tgt[base + j];
                float4 a4 = *(const float4*)&att[base + j];
                int4  dd4 = *(const int4*)&dly[base + j];
                float f0 = fminf(fmaxf(a4.x,0.f),1.f) * pow09(dd4.x);
                float f1 = fminf(fmaxf(a4.y,0.f),1.f) * pow09(dd4.y);
                float f2 = fminf(fmaxf(a4.z,0.f),1.f) * pow09(dd4.z);
                float f3 = fminf(fmaxf(a4.w,0.f),1.f) * pow09(dd4.w);
                atomicAdd(&sm_axon[t4.x], sig * f0);
                atomicAdd(&sm_axon[t4.y], sig * f1);
                atomicAdd(&sm_axon[t4.z], sig * f2);
                atomicAdd(&sm_axon[t4.w], sig * f3);
            }
        }
    }
    __syncthreads();

    ((float4*)(axon_o + (size_t)b * NUM_TARGET))[t] = ((const float4*)sm_axon)[t];
}

extern "C" void kernel_launch(void* const* d_in, const int* in_sizes, int n_in,
                              void* d_out, int out_size, void* d_ws, size_t ws_size,
                              hipStream_t stream) {
    const float* x     = (const float*)d_in[0];
    const float* mem   = (const float*)d_in[1];
    const float* refr  = (const float*)d_in[2];
    const float* W     = (const float*)d_in[3];
    const float* bias  = (const float*)d_in[4];
    const float* gamma = (const float*)d_in[5];
    const float* beta  = (const float*)d_in[6];
    const float* thr   = (const float*)d_in[7];
    const float* dec   = (const float*)d_in[8];
    const float* att   = (const float*)d_in[9];
    const int*   tgt   = (const int*)d_in[10];
    const int*   dly   = (const int*)d_in[11];

    float* out   = (float*)d_out;
    const int SEC = B_DIM * N_DIM;
    float* axon  = out;
    float* spike = out + SEC;
    float* nmem  = out + 2 * SEC;
    float* nref  = out + 3 * SEC;
    float* dhi   = nmem;
    float* dlo   = spike;

    const size_t pk_bytes = (size_t)N_DIM * BRN * sizeof(unsigned int); // 256 KB
    const bool use_pk = ws_size >= pk_bytes;
    unsigned int* pk = (unsigned int*)d_ws;

    if (use_pk)
        pack_kernel<<<(N_DIM * BRN) / 256, 256, 0, stream>>>(att, tgt, dly, pk);

    dim3 gg(B_DIM / BM, N_DIM / BN);   // 8 x 64
    gemm_mfma64_db_kernel<<<gg, 256, 0, stream>>>(x, W, bias, dhi, dlo);

    if (use_pk)
        fused_row_kernel<1><<<B_DIM, 1024, 0, stream>>>(
            dhi, dlo, mem, refr, gamma, beta, thr, dec, att, tgt, dly, pk,
            axon, spike, nmem, nref);
    else
        fused_row_kernel<0><<<B_DIM, 1024, 0, stream>>>(
            dhi, dlo, mem, refr, gamma, beta, thr, dec, att, tgt, dly, nullptr,
            axon, spike, nmem, nref);
}